// Round 5
// baseline (247.631 us; speedup 1.0000x reference)
//
#include <hip/hip_runtime.h>
#include <hip/hip_fp16.h>

// Problem geometry: inputs (B=2, D=64, H=64, W=64, C=32) fp32, C innermost.
// Pass1: Sobel (VALID) -> mag = sqrt(gx^2+gy^2+gz^2) at 62^3 per (b,c)
// Pass2: Sobel on mag -> out = sqrt(gx^2+gy^2) + gz^2 at 60^3
// Result: mean(|out_pred - out_hr|) over 2*32*60^3 = 13,824,000 elems.
//
// R5: same register z-streaming threads as R4 (that structure fixed the
// latency-bound regime), but fix the grid: R4 launched only 1024 (p1) / 720
// (p2) blocks = 2.8-4 blocks/CU -> occupancy capped at ~30%. Now z-chunks of
// 4 planes (grid.y 16/15) and, ws_size permitting, both batches merged into
// one launch (grid.z=4 / 2). VGPR=64 allows 8 waves/SIMD; feed it.

constexpr int BDIM = 256;
constexpr size_t IN_B = 8388608;   // 64*64*64*32 elements per batch
constexpr int IN_D = 131072;       // 64*64*32
constexpr int IN_H = 2048;         // 64*32
constexpr int M = 62;              // mag spatial dim
constexpr int F = 60;              // final spatial dim
constexpr int C = 32;
constexpr int MROW = M * C;                      // 1984
constexpr size_t MAGSZ = (size_t)M * M * MROW;   // halves per buffer
constexpr size_t PLANE = (size_t)M * MROW;       // halves per mag z-plane

__device__ __forceinline__ float2 ld2(const float* p) {
    return *reinterpret_cast<const float2*>(p);
}
__device__ __forceinline__ float2 ldh2(const __half* p) {
    return __half22float2(*reinterpret_cast<const __half2*>(p));
}

// ================= Pass 1: input -> fp16 magnitude, z-streamed =================
struct P1W { float2 A[4], B[4], C[4]; };   // per-plane partials for 4 output rows

__device__ __forceinline__ void p1_plane(const float* __restrict__ col, size_t zoff,
                                         const int jr[6], P1W& W)
{
    float2 SX[6], DX[6];
#pragma unroll
    for (int j = 0; j < 6; ++j) {
        const float* p = col + zoff + jr[j];
        float2 a = ld2(p), b = ld2(p + C), c = ld2(p + 2 * C);
        SX[j] = make_float2(a.x + 2.f * b.x + c.x, a.y + 2.f * b.y + c.y);
        DX[j] = make_float2(c.x - a.x, c.y - a.y);
    }
#pragma unroll
    for (int k = 0; k < 4; ++k) {
        W.A[k] = make_float2(SX[k].x + 2.f * SX[k+1].x + SX[k+2].x,
                             SX[k].y + 2.f * SX[k+1].y + SX[k+2].y);
        W.B[k] = make_float2(SX[k+2].x - SX[k].x, SX[k+2].y - SX[k].y);
        W.C[k] = make_float2(DX[k].x + 2.f * DX[k+1].x + DX[k+2].x,
                             DX[k].y + 2.f * DX[k+1].y + DX[k+2].y);
    }
}

__device__ __forceinline__ void p1_emit(const P1W& W0, const P1W& W1, const P1W& W2,
                                        __half* __restrict__ mag, size_t cb,
                                        int z, int y0, int kmax, bool xok)
{
    if (!xok) return;
#pragma unroll
    for (int k = 0; k < 4; ++k) {
        if (k < kmax) {
            float gxx = W2.A[k].x - W0.A[k].x;
            float gxy = W2.A[k].y - W0.A[k].y;
            float gyx = W0.B[k].x + 2.f * W1.B[k].x + W2.B[k].x;
            float gyy = W0.B[k].y + 2.f * W1.B[k].y + W2.B[k].y;
            float gzx = W0.C[k].x + 2.f * W1.C[k].x + W2.C[k].x;
            float gzy = W0.C[k].y + 2.f * W1.C[k].y + W2.C[k].y;
            float mx = sqrtf(gxx * gxx + gyx * gyx + gzx * gzx);
            float my = sqrtf(gxy * gxy + gyy * gyy + gzy * gzy);
            *reinterpret_cast<__half2*>(mag + ((size_t)z * M + (y0 + k)) * MROW + cb)
                = __floats2half2_rn(mx, my);
        }
    }
}

__global__ __launch_bounds__(BDIM) void sobel_mag_stream(
    const float* __restrict__ pred, const float* __restrict__ hr,
    __half* __restrict__ magbase, int bstart)
{
    const int xt = blockIdx.x & 3, yt = blockIdx.x >> 2;   // grid.x = 64
    const int zc = blockIdx.y;                             // [0,16)
    const int gz = blockIdx.z;                             // [0,2) or [0,4)
    const int b  = bstart + (gz >> 1);
    const float* __restrict__ in  = (gz & 1) ? hr : pred;
    __half*      __restrict__ mag = magbase + (size_t)gz * MAGSZ;

    const int y0 = yt * 4;
    const int z0 = zc * 4;
    const int zn = min(4, M - z0);        // 4, last chunk: 2
    const int kmax = min(4, M - y0);      // 4 or (last tile) 2
    const int xraw = xt * 16 + (threadIdx.x >> 4);
    const bool xok = xraw < M;
    const int x = min(xraw, M - 1);
    const int c2 = (threadIdx.x & 15) << 1;

    int jr[6];
#pragma unroll
    for (int j = 0; j < 6; ++j) jr[j] = min(y0 + j, 63) * IN_H;

    const float* col = in + (size_t)b * IN_B + (size_t)x * C + c2;
    const size_t cb = (size_t)x * C + c2;

    P1W W0, W1, W2;
    p1_plane(col, (size_t)(z0 + 0) * IN_D, jr, W0);
    p1_plane(col, (size_t)(z0 + 1) * IN_D, jr, W1);
    int z = 0;
    while (true) {
        p1_plane(col, (size_t)(z0 + z + 2) * IN_D, jr, W2);
        p1_emit(W0, W1, W2, mag, cb, z0 + z, y0, kmax, xok);
        if (++z >= zn) break;
        p1_plane(col, (size_t)(z0 + z + 2) * IN_D, jr, W0);
        p1_emit(W1, W2, W0, mag, cb, z0 + z, y0, kmax, xok);
        if (++z >= zn) break;
        p1_plane(col, (size_t)(z0 + z + 2) * IN_D, jr, W1);
        p1_emit(W2, W0, W1, mag, cb, z0 + z, y0, kmax, xok);
        if (++z >= zn) break;
    }
}

// ============ Pass 2: mag -> final, diff, partial sums, z-streamed ============
struct P2W { float2 A[2], B[2], C[2]; };

__device__ __forceinline__ void p2_plane(const __half* __restrict__ col, size_t zoff, P2W& W)
{
    float2 SX[4], DX[4];
#pragma unroll
    for (int j = 0; j < 4; ++j) {
        const __half* p = col + zoff + (size_t)j * MROW;
        float2 a = ldh2(p), b = ldh2(p + C), c = ldh2(p + 2 * C);
        SX[j] = make_float2(a.x + 2.f * b.x + c.x, a.y + 2.f * b.y + c.y);
        DX[j] = make_float2(c.x - a.x, c.y - a.y);
    }
#pragma unroll
    for (int k = 0; k < 2; ++k) {
        W.A[k] = make_float2(SX[k].x + 2.f * SX[k+1].x + SX[k+2].x,
                             SX[k].y + 2.f * SX[k+1].y + SX[k+2].y);
        W.B[k] = make_float2(SX[k+2].x - SX[k].x, SX[k+2].y - SX[k].y);
        W.C[k] = make_float2(DX[k].x + 2.f * DX[k+1].x + DX[k+2].x,
                             DX[k].y + 2.f * DX[k+1].y + DX[k+2].y);
    }
}

__device__ __forceinline__ void p2_emit(const P2W& P0, const P2W& P1, const P2W& P2,
                                        const P2W& H0, const P2W& H1, const P2W& H2,
                                        float& acc)
{
#pragma unroll
    for (int k = 0; k < 2; ++k) {
        float gxPx = P2.A[k].x - P0.A[k].x;
        float gxPy = P2.A[k].y - P0.A[k].y;
        float gyPx = P0.B[k].x + 2.f * P1.B[k].x + P2.B[k].x;
        float gyPy = P0.B[k].y + 2.f * P1.B[k].y + P2.B[k].y;
        float gzPx = P0.C[k].x + 2.f * P1.C[k].x + P2.C[k].x;
        float gzPy = P0.C[k].y + 2.f * P1.C[k].y + P2.C[k].y;
        float gxHx = H2.A[k].x - H0.A[k].x;
        float gxHy = H2.A[k].y - H0.A[k].y;
        float gyHx = H0.B[k].x + 2.f * H1.B[k].x + H2.B[k].x;
        float gyHy = H0.B[k].y + 2.f * H1.B[k].y + H2.B[k].y;
        float gzHx = H0.C[k].x + 2.f * H1.C[k].x + H2.C[k].x;
        float gzHy = H0.C[k].y + 2.f * H1.C[k].y + H2.C[k].y;
        float oPx = sqrtf(gxPx * gxPx + gyPx * gyPx) + gzPx * gzPx;
        float oPy = sqrtf(gxPy * gxPy + gyPy * gyPy) + gzPy * gzPy;
        float oHx = sqrtf(gxHx * gxHx + gyHx * gyHx) + gzHx * gzHx;
        float oHy = sqrtf(gxHy * gxHy + gyHy * gyHy) + gzHy * gzHy;
        acc += fabsf(oPx - oHx) + fabsf(oPy - oHy);
    }
}

__global__ __launch_bounds__(BDIM) void sobel2_stream(
    const __half* __restrict__ magbase, float* __restrict__ partial, int bstart)
{
    const int xt = blockIdx.x & 3, yt = blockIdx.x >> 2;   // grid.x = 120
    const int zc = blockIdx.y;                             // [0,15)
    const int b  = bstart + blockIdx.z;
    const __half* __restrict__ magP = magbase + (size_t)(2 * blockIdx.z) * MAGSZ;
    const __half* __restrict__ magH = magP + MAGSZ;
    const int y0 = yt * 2;
    const int z0 = zc * 4;
    const int xraw = xt * 16 + (threadIdx.x >> 4);
    const bool xok = xraw < F;
    const int x = min(xraw, F - 1);
    const int c2 = (threadIdx.x & 15) << 1;

    const size_t colo = (size_t)y0 * MROW + (size_t)x * C + c2;
    const __half* colP = magP + colo;
    const __half* colH = magH + colo;

    P2W P0, P1, P2, H0, H1, H2;
    p2_plane(colP, (size_t)(z0 + 0) * PLANE, P0);
    p2_plane(colH, (size_t)(z0 + 0) * PLANE, H0);
    p2_plane(colP, (size_t)(z0 + 1) * PLANE, P1);
    p2_plane(colH, (size_t)(z0 + 1) * PLANE, H1);
    float acc = 0.f;
    int z = 0;
    while (true) {
        p2_plane(colP, (size_t)(z0 + z + 2) * PLANE, P2);
        p2_plane(colH, (size_t)(z0 + z + 2) * PLANE, H2);
        if (xok) p2_emit(P0, P1, P2, H0, H1, H2, acc);
        if (++z >= 4) break;
        p2_plane(colP, (size_t)(z0 + z + 2) * PLANE, P0);
        p2_plane(colH, (size_t)(z0 + z + 2) * PLANE, H0);
        if (xok) p2_emit(P1, P2, P0, H1, H2, H0, acc);
        if (++z >= 4) break;
        p2_plane(colP, (size_t)(z0 + z + 2) * PLANE, P1);
        p2_plane(colH, (size_t)(z0 + z + 2) * PLANE, H1);
        if (xok) p2_emit(P2, P0, P1, H2, H0, H1, acc);
        if (++z >= 4) break;
    }

    // block reduction: wave64 shuffle, then across the 4 waves via LDS
    for (int o = 32; o > 0; o >>= 1) acc += __shfl_down(acc, o, 64);
    __shared__ float sred[BDIM / 64];
    const int lane = threadIdx.x & 63, wv = threadIdx.x >> 6;
    if (lane == 0) sred[wv] = acc;
    __syncthreads();
    if (threadIdx.x == 0) {
        float t = 0.f;
#pragma unroll
        for (int i = 0; i < BDIM / 64; ++i) t += sred[i];
        partial[(size_t)b * 1800 + (size_t)zc * 120 + blockIdx.x] = t;
    }
}

// -------- Finalize: sum 3600 partials in double, write mean --------
__global__ __launch_bounds__(BDIM) void finalize_kernel(
    const float* __restrict__ partial, float* __restrict__ out)
{
    double a = 0.0;
    for (int i = threadIdx.x; i < 3600; i += BDIM) a += (double)partial[i];
    for (int o = 32; o > 0; o >>= 1) a += __shfl_down(a, o, 64);
    __shared__ double sd[BDIM / 64];
    const int lane = threadIdx.x & 63, wv = threadIdx.x >> 6;
    if (lane == 0) sd[wv] = a;
    __syncthreads();
    if (threadIdx.x == 0) {
        double t = 0.0;
#pragma unroll
        for (int i = 0; i < BDIM / 64; ++i) t += sd[i];
        out[0] = (float)(t / 13824000.0);
    }
}

extern "C" void kernel_launch(void* const* d_in, const int* in_sizes, int n_in,
                              void* d_out, int out_size, void* d_ws, size_t ws_size,
                              hipStream_t stream)
{
    const float* pred = (const float*)d_in[0];
    const float* hr   = (const float*)d_in[1];

    // ws layout: [0, 14.4KB): 3600 float partials (fully overwritten each call)
    //            [64KB, ...): mag buffers fp16; 2 buffers (29.1 MiB) sequential,
    //            4 buffers (58.2 MiB) merged-batch if ws_size allows.
    float* partial = (float*)d_ws;
    __half* magbase = (__half*)((char*)d_ws + 65536);

    const bool merged = ws_size >= (size_t)65536 + 4 * MAGSZ * sizeof(__half);
    if (merged) {
        // One launch per pass: grid.z covers b x {pred,hr} / b.
        sobel_mag_stream<<<dim3(64, 16, 4), BDIM, 0, stream>>>(pred, hr, magbase, 0);
        sobel2_stream<<<dim3(120, 15, 2), BDIM, 0, stream>>>(magbase, partial, 0);
    } else {
        for (int b = 0; b < 2; ++b) {
            sobel_mag_stream<<<dim3(64, 16, 2), BDIM, 0, stream>>>(pred, hr, magbase, b);
            sobel2_stream<<<dim3(120, 15, 1), BDIM, 0, stream>>>(magbase, partial, b);
        }
    }
    finalize_kernel<<<1, BDIM, 0, stream>>>(partial, (float*)d_out);
}